// Round 7
// baseline (194.761 us; speedup 1.0000x reference)
//
#include <hip/hip_runtime.h>

typedef __attribute__((ext_vector_type(8))) short short8;     // 8 bf16 MFMA operand
typedef __attribute__((ext_vector_type(4))) float f32x4;
typedef __attribute__((ext_vector_type(8))) unsigned short ushort8v;

// B=2, T=2048, D_IN=1024, H=16, D_HEAD=64, D_INNER=1024, M=B*T=4096

__device__ __forceinline__ unsigned short f2bf(float f) {
  union { float f; unsigned int u; } x; x.f = f;
  unsigned int r = x.u + 0x7FFFu + ((x.u >> 16) & 1u);   // RNE
  return (unsigned short)(r >> 16);
}

__device__ __forceinline__ void gload_lds16(const void* g, void* l) {
  __builtin_amdgcn_global_load_lds(
      (const __attribute__((address_space(1))) void*)g,
      (__attribute__((address_space(3))) void*)l, 16, 0, 0);
}

// ---------------- fused prep: bias_init + x->bf16 + 4 weight transposes ----------------
// grid: [0,4096) cvt x | [4096,7168) Wq/Wk/Wv transpose | [7168,7232) Wo | [7232,7488) bias

__global__ __launch_bounds__(256) void prep(
    const float* __restrict__ x,
    const float* __restrict__ Wq, const float* __restrict__ Wk, const float* __restrict__ Wv,
    const float* __restrict__ Wo, const float* __restrict__ bo,
    unsigned short* __restrict__ xb,
    unsigned short* __restrict__ wqt, unsigned short* __restrict__ wkt,
    unsigned short* __restrict__ wvt, unsigned short* __restrict__ wot,
    float* __restrict__ out) {
  __shared__ float tile[32][33];
  int b = blockIdx.x;
  if (b < 4096) {                     // x -> bf16, 4 elems/thread
    int i = (b * 256 + threadIdx.x) * 4;
    float4 f = *(const float4*)(x + i);
    ushort4 o;
    o.x = f2bf(f.x); o.y = f2bf(f.y); o.z = f2bf(f.z); o.w = f2bf(f.w);
    *(ushort4*)(xb + i) = o;
  } else if (b < 7168) {              // W^T for Wq/Wk/Wv (1024x1024)
    int idx = b - 4096;
    int z = idx >> 10, rem = idx & 1023;
    const float* src = (z == 0) ? Wq : (z == 1) ? Wk : Wv;
    unsigned short* dst = (z == 0) ? wqt : (z == 1) ? wkt : wvt;
    int kx = (rem & 31) * 32, ny = (rem >> 5) * 32;
    int tx = threadIdx.x & 31, ty = threadIdx.x >> 5;
    #pragma unroll
    for (int r = 0; r < 32; r += 8)
      tile[ty + r][tx] = src[(size_t)(kx + ty + r) * 1024 + ny + tx];
    __syncthreads();
    #pragma unroll
    for (int r = 0; r < 32; r += 8)
      dst[(size_t)(ny + ty + r) * 1024 + kx + tx] = f2bf(tile[tx][ty + r]);
  } else if (b < 7232) {              // Wo^T (1024x64 -> 64x1024)
    int idx = b - 7168;
    int kx = (idx & 31) * 32, ny = (idx >> 5) * 32;
    int tx = threadIdx.x & 31, ty = threadIdx.x >> 5;
    #pragma unroll
    for (int r = 0; r < 32; r += 8)
      tile[ty + r][tx] = Wo[(size_t)(kx + ty + r) * 64 + ny + tx];
    __syncthreads();
    #pragma unroll
    for (int r = 0; r < 32; r += 8)
      wot[(size_t)(ny + ty + r) * 1024 + kx + tx] = f2bf(tile[tx][ty + r]);
  } else {                            // seed out with bias (out is re-poisoned each call)
    int t = (b - 7232) * 256 + threadIdx.x;  // 65536 float4s
    float4 bi = *(const float4*)(bo + (t & 15) * 4);
    *(float4*)(out + (size_t)t * 4) = bi;
  }
}

// ---------------- QKV projection GEMM, BK=64 with XOR-swizzled staging ----------------
// z=0: Q = x·Wq (scaled 1/32) -> [b][h][t][d]; z=1: K -> [b][h][t][d];
// z=2: V^T computed directly (A=Wv^T, B=x) -> [b][h][d][t]

__global__ __launch_bounds__(256) void qkv_gemm(
    const unsigned short* __restrict__ Xb,
    const unsigned short* __restrict__ Wqt, const unsigned short* __restrict__ Wkt,
    const unsigned short* __restrict__ Wvt,
    unsigned short* __restrict__ Oq, unsigned short* __restrict__ Ok,
    unsigned short* __restrict__ Ovt) {
  constexpr int Kd = 1024;
  __shared__ __align__(16) unsigned short As[128 * 64];
  __shared__ __align__(16) unsigned short Bs[128 * 64];
  int z = blockIdx.z;
  int m0, n0;
  const unsigned short *Arow, *Brow;
  if (z == 2) {
    m0 = blockIdx.y * 128; n0 = blockIdx.x * 128;
    Arow = Wvt; Brow = Xb;
  } else {
    m0 = blockIdx.x * 128; n0 = blockIdx.y * 128;
    Arow = Xb; Brow = (z == 0) ? Wqt : Wkt;
  }
  int tid = threadIdx.x, lane = tid & 63, wave = tid >> 6;
  int wm = wave >> 1, wn = wave & 1;
  int l15 = lane & 15, quad = lane >> 4;
  int swz = l15 & 7;

  f32x4 acc[4][4] = {};

  for (int k0 = 0; k0 < Kd; k0 += 64) {
    __syncthreads();
    #pragma unroll
    for (int r = 0; r < 4; ++r) {
      int i = tid + 256 * r;
      int row = i >> 3, c8 = i & 7;
      int gc8 = c8 ^ (row & 7);
      gload_lds16(Arow + (size_t)(m0 + row) * Kd + k0 + gc8 * 8, &As[i * 8]);
    }
    #pragma unroll
    for (int r = 0; r < 4; ++r) {
      int i = tid + 256 * r;
      int row = i >> 3, c8 = i & 7;
      int gc8 = c8 ^ (row & 7);
      gload_lds16(Brow + (size_t)(n0 + row) * Kd + k0 + gc8 * 8, &Bs[i * 8]);
    }
    __syncthreads();
    short8 af[4][2], bf[4][2];
    #pragma unroll
    for (int s = 0; s < 2; ++s) {
      #pragma unroll
      for (int i = 0; i < 4; ++i)
        af[i][s] = *(const short8*)&As[(wm * 64 + i * 16 + l15) * 64 + (((s << 2) + quad) ^ swz) * 8];
      #pragma unroll
      for (int j = 0; j < 4; ++j)
        bf[j][s] = *(const short8*)&Bs[(wn * 64 + j * 16 + l15) * 64 + (((s << 2) + quad) ^ swz) * 8];
    }
    #pragma unroll
    for (int s = 0; s < 2; ++s)
      #pragma unroll
      for (int i = 0; i < 4; ++i)
        #pragma unroll
        for (int j = 0; j < 4; ++j)
          acc[i][j] = __builtin_amdgcn_mfma_f32_16x16x32_bf16(af[i][s], bf[j][s], acc[i][j], 0, 0, 0);
  }

  if (z == 2) {
    #pragma unroll
    for (int i = 0; i < 4; ++i) {
      int dmbase = m0 + wm * 64 + i * 16 + quad * 4;
      #pragma unroll
      for (int j = 0; j < 4; ++j) {
        int tn = n0 + wn * 64 + j * 16 + l15;
        int b = tn >> 11, t = tn & 2047;
        #pragma unroll
        for (int r = 0; r < 4; ++r) {
          int dm = dmbase + r;
          int h = dm >> 6, d = dm & 63;
          Ovt[(((size_t)(b * 16 + h) * 64 + d) << 11) + t] = f2bf(acc[i][j][r]);
        }
      }
    }
  } else {
    unsigned short* O = (z == 0) ? Oq : Ok;
    float scale = (z == 0) ? 0.03125f : 1.0f;  // 1/sqrt(1024) folded into Q
    #pragma unroll
    for (int i = 0; i < 4; ++i) {
      int mbase = m0 + wm * 64 + i * 16 + quad * 4;
      #pragma unroll
      for (int j = 0; j < 4; ++j) {
        int n = n0 + wn * 64 + j * 16 + l15;
        int h = n >> 6, d = n & 63;
        #pragma unroll
        for (int r = 0; r < 4; ++r) {
          int mm = mbase + r;
          int b = mm >> 11, t = mm & 2047;
          size_t off = (((size_t)(b * 16 + h) * 2048 + t) << 6) + d;
          O[off] = f2bf(acc[i][j][r] * scale);
        }
      }
    }
  }
}

// ---------------- fused causal flash attention v5 ----------------
// 32 q/wave (jq=2): each K/V frag feeds 2 MFMAs. V frags read DIRECT from
// global (V^T [d][t] = perfect B-frag), offloading LDS->VMEM. K staged in
// LDS (block-shared, reg-prefetched). Balanced pairs (p, 31-p): 33 trips
// uniform. 512 blocks x 2 waves (2 blocks/CU -> barrier drains overlap).

__global__ __launch_bounds__(128, 2) void attn5(
    const unsigned short* __restrict__ Qg, const unsigned short* __restrict__ Kg,
    const unsigned short* __restrict__ Vtg, unsigned short* __restrict__ Yg) {
  constexpr int T = 2048;
  __shared__ __align__(16) unsigned short Ks[64 * 72];
  __shared__ __align__(16) unsigned short Ps[2][32 * 72];
  int bh = blockIdx.y;
  int pp = (blockIdx.x + blockIdx.y) & 15;   // L2 swizzle over pairs
  int tid = threadIdx.x, lane = tid & 63, wave = tid >> 6;
  int l15 = lane & 15, quad = lane >> 4;
  const unsigned short* Qb = Qg + (size_t)bh * T * 64;
  const unsigned short* Kb = Kg + (size_t)bh * T * 64;
  const unsigned short* Vb = Vtg + (size_t)bh * 64 * T;
  int h = bh & 15, b = bh >> 4;

  for (int phase = 0; phase < 2; ++phase) {
    int qt = phase ? (31 - pp) : pp;          // pair (pp, 31-pp): 33 trips total
    int qw = qt * 64 + wave * 32;

    // Q as B-operand frags (regs): lane n=q(l15), k=d(quad*8+32s)
    short8 qf[2][2];
    #pragma unroll
    for (int jq = 0; jq < 2; ++jq)
      #pragma unroll
      for (int s = 0; s < 2; ++s)
        qf[jq][s] = *(const short8*)(Qb + (size_t)(qw + jq * 16 + l15) * 64 + quad * 8 + 32 * s);

    f32x4 Oacc[2][4] = {};
    float m_run[2] = {-__builtin_inff(), -__builtin_inff()};
    float l_run[2] = {0.f, 0.f};

    // prefetch K tile 0 (4 x 16B per thread; 128 threads cover 64x64)
    ushort8v kpre[4];
    #pragma unroll
    for (int r = 0; r < 4; ++r) {
      int i = tid + 128 * r;
      kpre[r] = *(const ushort8v*)(Kb + (size_t)(i >> 3) * 64 + (i & 7) * 8);
    }

    for (int kt = 0; kt <= qt; ++kt) {
      __syncthreads();
      #pragma unroll
      for (int r = 0; r < 4; ++r) {
        int i = tid + 128 * r;
        *(ushort8v*)&Ks[(i >> 3) * 72 + (i & 7) * 8] = kpre[r];
      }
      __syncthreads();
      if (kt < qt) {  // prefetch next K tile while computing
        #pragma unroll
        for (int r = 0; r < 4; ++r) {
          int i = tid + 128 * r;
          kpre[r] = *(const ushort8v*)(Kb + (size_t)((kt + 1) * 64 + (i >> 3)) * 64 + (i & 7) * 8);
        }
      }
      // V frags for THIS iter, direct from global (latency covered by S+softmax)
      short8 vf[4][2];
      #pragma unroll
      for (int jd = 0; jd < 4; ++jd)
        #pragma unroll
        for (int s = 0; s < 2; ++s)
          vf[jd][s] = *(const short8*)(Vb + (size_t)(jd * 16 + l15) * T + kt * 64 + s * 32 + quad * 8);

      // S^T = K·Q^T : rows=tok(64), cols=q(32); K frags reused across jq
      f32x4 S[4][2] = {};
      #pragma unroll
      for (int s = 0; s < 2; ++s)
        #pragma unroll
        for (int mi = 0; mi < 4; ++mi) {
          short8 kf = *(const short8*)&Ks[(mi * 16 + l15) * 72 + quad * 8 + 32 * s];
          #pragma unroll
          for (int jq = 0; jq < 2; ++jq)
            S[mi][jq] = __builtin_amdgcn_mfma_f32_16x16x32_bf16(kf, qf[jq][s], S[mi][jq], 0, 0, 0);
        }

      if (kt == qt) {  // diagonal tile: mask tok_local > q_local
        #pragma unroll
        for (int mi = 0; mi < 4; ++mi) {
          int tokl = mi * 16 + quad * 4;
          #pragma unroll
          for (int jq = 0; jq < 2; ++jq) {
            int ql = wave * 32 + jq * 16 + l15;
            #pragma unroll
            for (int r = 0; r < 4; ++r)
              if (tokl + r > ql) S[mi][jq][r] = -__builtin_inff();
          }
        }
      }

      // online softmax along tok per jq block
      float alpha[2];
      #pragma unroll
      for (int jq = 0; jq < 2; ++jq) {
        float vmax = -__builtin_inff();
        #pragma unroll
        for (int mi = 0; mi < 4; ++mi)
          #pragma unroll
          for (int r = 0; r < 4; ++r)
            vmax = fmaxf(vmax, S[mi][jq][r]);
        vmax = fmaxf(vmax, __shfl_xor(vmax, 16));
        vmax = fmaxf(vmax, __shfl_xor(vmax, 32));
        float mnew = fmaxf(m_run[jq], vmax);
        alpha[jq] = __expf(m_run[jq] - mnew);
        m_run[jq] = mnew;
        float rs = 0.f;
        #pragma unroll
        for (int mi = 0; mi < 4; ++mi) {
          float p0 = __expf(S[mi][jq][0] - mnew);
          float p1 = __expf(S[mi][jq][1] - mnew);
          float p2 = __expf(S[mi][jq][2] - mnew);
          float p3 = __expf(S[mi][jq][3] - mnew);
          rs += (p0 + p1) + (p2 + p3);
          union { float f; unsigned int u; } a0{p0}, a1{p1}, a2{p2}, a3{p3};
          uint2 pk;
          pk.x = ((a0.u + 0x8000u) >> 16) | ((a1.u + 0x8000u) & 0xFFFF0000u);
          pk.y = ((a2.u + 0x8000u) >> 16) | ((a3.u + 0x8000u) & 0xFFFF0000u);
          *(uint2*)&Ps[wave][(jq * 16 + l15) * 72 + mi * 16 + quad * 4] = pk;
        }
        rs += __shfl_xor(rs, 16);
        rs += __shfl_xor(rs, 32);
        l_run[jq] = l_run[jq] * alpha[jq] + rs;
      }

      // rescale O (alpha indexed by q=l15 -> redistribute to C rows quad*4+r)
      #pragma unroll
      for (int mq = 0; mq < 2; ++mq)
        #pragma unroll
        for (int r = 0; r < 4; ++r) {
          float a = __shfl(alpha[mq], quad * 4 + r);
          #pragma unroll
          for (int jd = 0; jd < 4; ++jd)
            Oacc[mq][jd][r] *= a;
        }

      // O += P·V  (A=P from LDS, B=V^T global frags; vf reused across mq)
      #pragma unroll
      for (int s = 0; s < 2; ++s) {
        short8 pf[2];
        #pragma unroll
        for (int mq = 0; mq < 2; ++mq)
          pf[mq] = *(const short8*)&Ps[wave][(mq * 16 + l15) * 72 + s * 32 + quad * 8];
        #pragma unroll
        for (int jd = 0; jd < 4; ++jd)
          #pragma unroll
          for (int mq = 0; mq < 2; ++mq)
            Oacc[mq][jd] = __builtin_amdgcn_mfma_f32_16x16x32_bf16(pf[mq], vf[jd][s], Oacc[mq][jd], 0, 0, 0);
      }
    }

    // finalize phase: O/l, write Y [b*T+q][h*64+d] bf16
    #pragma unroll
    for (int mq = 0; mq < 2; ++mq)
      #pragma unroll
      for (int r = 0; r < 4; ++r) {
        float linv = 1.f / __shfl(l_run[mq], quad * 4 + r);
        int q = qw + mq * 16 + quad * 4 + r;
        size_t row = (size_t)(b * 2048 + q) * 1024 + h * 64;
        #pragma unroll
        for (int jd = 0; jd < 4; ++jd)
          Yg[row + jd * 16 + l15] = f2bf(Oacc[mq][jd][r] * linv);
      }
  }
}

// ---------------- out projection: split-K atomics onto bias-seeded out ----------------

__global__ __launch_bounds__(256) void oproj(
    const unsigned short* __restrict__ Y, const unsigned short* __restrict__ Wot,
    float* __restrict__ out) {
  __shared__ __align__(16) unsigned short As[64 * 32];
  __shared__ __align__(16) unsigned short Bs[64 * 32];
  int m0 = blockIdx.x * 64;
  int kbase = blockIdx.y * 256;  // 4-way split-K
  int tid = threadIdx.x, lane = tid & 63, wave = tid >> 6;
  int l15 = lane & 15, quad = lane >> 4;
  f32x4 acc[4] = {};
  for (int k0 = kbase; k0 < kbase + 256; k0 += 32) {
    __syncthreads();
    {
      int row = tid >> 2, c8 = (tid & 3) * 8;
      gload_lds16(Y + (size_t)(m0 + row) * 1024 + k0 + c8, &As[tid * 8]);
      gload_lds16(Wot + (size_t)row * 1024 + k0 + c8, &Bs[tid * 8]);
    }
    __syncthreads();
    short8 af = *(const short8*)&As[(wave * 16 + l15) * 32 + quad * 8];
    #pragma unroll
    for (int j = 0; j < 4; ++j) {
      short8 bf = *(const short8*)&Bs[(j * 16 + l15) * 32 + quad * 8];
      acc[j] = __builtin_amdgcn_mfma_f32_16x16x32_bf16(af, bf, acc[j], 0, 0, 0);
    }
  }
  #pragma unroll
  for (int j = 0; j < 4; ++j) {
    int n = j * 16 + l15;
    #pragma unroll
    for (int r = 0; r < 4; ++r) {
      int m = m0 + wave * 16 + quad * 4 + r;
      atomicAdd(&out[(size_t)m * 64 + n], acc[j][r]);
    }
  }
}

// ---------------- launcher (4 kernels total) ----------------

extern "C" void kernel_launch(void* const* d_in, const int* in_sizes, int n_in,
                              void* d_out, int out_size, void* d_ws, size_t ws_size,
                              hipStream_t stream) {
  const float* x  = (const float*)d_in[0];
  const float* Wq = (const float*)d_in[1];
  const float* Wk = (const float*)d_in[2];
  const float* Wv = (const float*)d_in[3];
  const float* Wo = (const float*)d_in[4];
  const float* bo = (const float*)d_in[5];
  float* out = (float*)d_out;
  char* ws = (char*)d_ws;

  unsigned short* xb  = (unsigned short*)(ws);                       // 8 MB  [4096][1024]
  unsigned short* wqt = (unsigned short*)(ws + (8ull << 20));        // 2 MB  Wq^T
  unsigned short* wkt = (unsigned short*)(ws + (10ull << 20));       // 2 MB
  unsigned short* wvt = (unsigned short*)(ws + (12ull << 20));       // 2 MB
  unsigned short* wot = (unsigned short*)(ws + (14ull << 20));       // 128 KB Wo^T
  unsigned short* q   = (unsigned short*)(ws + (15ull << 20));       // 8 MB  [b][h][t][d]
  unsigned short* k   = (unsigned short*)(ws + (23ull << 20));       // 8 MB  [b][h][t][d]
  unsigned short* vt  = (unsigned short*)(ws + (31ull << 20));       // 8 MB  [b][h][d][t]
  unsigned short* y   = (unsigned short*)(ws + (39ull << 20));       // 8 MB  [4096][1024]

  prep<<<7488, 256, 0, stream>>>(x, Wq, Wk, Wv, Wo, bo, xb, wqt, wkt, wvt, wot, out);
  qkv_gemm<<<dim3(32, 8, 3), 256, 0, stream>>>(xb, wqt, wkt, wvt, q, k, vt);
  attn5<<<dim3(16, 32), 128, 0, stream>>>(q, k, vt, y);
  oproj<<<dim3(64, 4), 256, 0, stream>>>(y, wot, out);
}